// Round 1
// baseline (188.549 us; speedup 1.0000x reference)
//
#include <hip/hip_runtime.h>
#include <hip/hip_bf16.h>
#include <stdint.h>

#define T_STEPS 86
#define HDIM    64
#define VOCABSZ 257
#define ROWS    16        // batch rows per block
#define NTHREADS 512      // 8 waves

typedef __attribute__((ext_vector_type(8))) short short8;
typedef __attribute__((ext_vector_type(4))) float f32x4;

__device__ __forceinline__ ushort f2bf(float x){
    union { float f; uint32_t u; } v; v.f = x;
    uint32_t r = v.u + 0x7fffu + ((v.u >> 16) & 1u);
    return (ushort)(r >> 16);
}
__device__ __forceinline__ float bf2f(ushort h){
    union { uint32_t u; float f; } v; v.u = ((uint32_t)h) << 16;
    return v.f;
}
__device__ __forceinline__ float sig_(float x){
    return __fdividef(1.f, 1.f + __expf(-x));
}
__device__ __forceinline__ float tanh_(float x){
    float e = __expf(2.f * x);
    return 1.f - __fdividef(2.f, e + 1.f);
}

__global__ __launch_bounds__(NTHREADS) void lstm_fused(
    const int*   __restrict__ idx,
    const float* __restrict__ wte,
    const float* __restrict__ W_ih,
    const float* __restrict__ W_hh,
    const float* __restrict__ b_ih,
    const float* __restrict__ b_hh,
    const float* __restrict__ lm_W,
    const float* __restrict__ lm_b,
    float*       __restrict__ out,
    int B)
{
    // A operand staging: [ROWS][128] bf16, [0:64)=emb(t), [64:128)=h(t-1). XOR-swizzled.
    __shared__ __align__(16) ushort a_hi[ROWS * 128];
    __shared__ __align__(16) ushort a_lo[ROWS * 128];
    __shared__ float g_lds[ROWS * 260];   // gate preactivations bounce, padded stride

    const int tid  = threadIdx.x;
    const int wave = tid >> 6;
    const int lane = tid & 63;
    const int lmod = lane & 15;
    const int lhi  = lane >> 4;
    const int rbase = blockIdx.x * ROWS;

    // ---- pack gate-weight B-frags into registers (wave owns gate cols [wave*32, wave*32+32)) ----
    // B-frag layout for mfma_f32_16x16x32_bf16: lane holds B^T[col = lane&15][k = (lane>>4)*8 + e]
    short8 wbh[2][4], wbl[2][4];
    float  gbias[2];
#pragma unroll
    for (int n = 0; n < 2; ++n) {
        const int col = wave * 32 + n * 16 + lmod;
        gbias[n] = b_ih[col] + b_hh[col];
#pragma unroll
        for (int kt = 0; kt < 4; ++kt) {
            const int k0 = (kt & 1) * 32 + lhi * 8;
            const float* src = (kt < 2 ? W_ih : W_hh) + col * HDIM + k0;
            short8 h8, l8;
#pragma unroll
            for (int e = 0; e < 8; ++e) {
                float f   = src[e];
                ushort hh = f2bf(f);
                h8[e] = (short)hh;
                l8[e] = (short)f2bf(f - bf2f(hh));
            }
            wbh[n][kt] = h8; wbl[n][kt] = l8;
        }
    }

    // ---- pack lm_W B-frags (17 N-tiles of 16 vocab cols over 8 waves: wave0 gets 3, rest 2) ----
    const int nstart = (wave == 0) ? 0 : (2 * wave + 1);
    const int ncnt   = (wave == 0) ? 3 : 2;
    short8 lmh[3][2], lml[3][2];
    float  lmbias[3];
#pragma unroll
    for (int ni = 0; ni < 3; ++ni) {
        const int v  = (nstart + ni) * 16 + lmod;
        const bool ok = (ni < ncnt) && (v < VOCABSZ);
        lmbias[ni] = ok ? lm_b[v] : 0.f;
#pragma unroll
        for (int kt = 0; kt < 2; ++kt) {
            const int k0 = kt * 32 + lhi * 8;
            short8 h8, l8;
#pragma unroll
            for (int e = 0; e < 8; ++e) {
                float f   = ok ? lm_W[v * HDIM + k0 + e] : 0.f;
                ushort hh = f2bf(f);
                h8[e] = (short)hh;
                l8[e] = (short)f2bf(f - bf2f(hh));
            }
            lmh[ni][kt] = h8; lml[ni][kt] = l8;
        }
    }

    // ---- init: zero h-slot, stage emb(t=0) ----
    for (int i = tid; i < ROWS * HDIM; i += NTHREADS) {
        const int r = i >> 6, j = i & 63;
        const int ix = (r * 128 + 64 + j) ^ ((r & 7) << 3);
        a_hi[ix] = 0; a_lo[ix] = 0;
    }
    for (int i = tid; i < ROWS * 16; i += NTHREADS) {
        const int r = i >> 4, j4 = (i & 15) * 4;
        const int token = idx[(rbase + r) * T_STEPS + 0];
        const float4 vv = *(const float4*)(wte + (size_t)token * HDIM + j4);
        const float fv[4] = {vv.x, vv.y, vv.z, vv.w};
#pragma unroll
        for (int e = 0; e < 4; ++e) {
            const ushort hh = f2bf(fv[e]);
            const int ix = (r * 128 + j4 + e) ^ ((r & 7) << 3);
            a_hi[ix] = hh;
            a_lo[ix] = f2bf(fv[e] - bf2f(hh));
        }
    }

    float cstate[2] = {0.f, 0.f};
    const int ew_j  = tid & 63;
    const int ew_rq = tid >> 6;

    for (int t = 0; t < T_STEPS; ++t) {
        __syncthreads();   // B1: a_lds = {emb(t), h(t-1)} visible

        // ---- gates MFMA: [16 x 128] @ [128 x 256] (3-term bf16 split) ----
        f32x4 acc0 = {gbias[0], gbias[0], gbias[0], gbias[0]};
        f32x4 acc1 = {gbias[1], gbias[1], gbias[1], gbias[1]};
#pragma unroll
        for (int kt = 0; kt < 4; ++kt) {
            const int ix = (lmod * 128 + kt * 32 + lhi * 8) ^ ((lmod & 7) << 3);
            const short8 ah = *(const short8*)(a_hi + ix);
            const short8 al = *(const short8*)(a_lo + ix);
            acc0 = __builtin_amdgcn_mfma_f32_16x16x32_bf16(ah, wbh[0][kt], acc0, 0, 0, 0);
            acc0 = __builtin_amdgcn_mfma_f32_16x16x32_bf16(ah, wbl[0][kt], acc0, 0, 0, 0);
            acc0 = __builtin_amdgcn_mfma_f32_16x16x32_bf16(al, wbh[0][kt], acc0, 0, 0, 0);
            acc1 = __builtin_amdgcn_mfma_f32_16x16x32_bf16(ah, wbh[1][kt], acc1, 0, 0, 0);
            acc1 = __builtin_amdgcn_mfma_f32_16x16x32_bf16(ah, wbl[1][kt], acc1, 0, 0, 0);
            acc1 = __builtin_amdgcn_mfma_f32_16x16x32_bf16(al, wbh[1][kt], acc1, 0, 0, 0);
        }
        // D layout: row = (lane>>4)*4 + e, col = lane&15
#pragma unroll
        for (int e = 0; e < 4; ++e) {
            const int row = lhi * 4 + e;
            g_lds[row * 260 + wave * 32 + lmod]      = acc0[e];
            g_lds[row * 260 + wave * 32 + 16 + lmod] = acc1[e];
        }
        __syncthreads();   // B2: g_lds ready

        // ---- elementwise LSTM (c in regs), write h(t) hi/lo back to a_lds ----
#pragma unroll
        for (int p = 0; p < 2; ++p) {
            const int r = ew_rq + p * 8;
            const float* gr = g_lds + r * 260;
            const float iv = gr[ew_j];
            const float fv = gr[64 + ew_j];
            const float gv = gr[128 + ew_j];
            const float ov = gr[192 + ew_j];
            const float cn = sig_(fv) * cstate[p] + sig_(iv) * tanh_(gv);
            cstate[p] = cn;
            const float hv = sig_(ov) * tanh_(cn);
            const ushort hh = f2bf(hv);
            const int ix = (r * 128 + 64 + ew_j) ^ ((r & 7) << 3);
            a_hi[ix] = hh;
            a_lo[ix] = f2bf(hv - bf2f(hh));
        }
        // ---- stage emb(t+1) ----
        if (t + 1 < T_STEPS) {
            for (int i = tid; i < ROWS * 16; i += NTHREADS) {
                const int r = i >> 4, j4 = (i & 15) * 4;
                const int token = idx[(rbase + r) * T_STEPS + (t + 1)];
                const float4 vv = *(const float4*)(wte + (size_t)token * HDIM + j4);
                const float fv[4] = {vv.x, vv.y, vv.z, vv.w};
#pragma unroll
                for (int e = 0; e < 4; ++e) {
                    const ushort hh = f2bf(fv[e]);
                    const int ix = (r * 128 + j4 + e) ^ ((r & 7) << 3);
                    a_hi[ix] = hh;
                    a_lo[ix] = f2bf(fv[e] - bf2f(hh));
                }
            }
        }
        __syncthreads();   // B3: h(t) visible

        // ---- logits MFMA: [16 x 64] @ [64 x 257] (3-term split) + store ----
        short8 lah[2], lal[2];
#pragma unroll
        for (int kt = 0; kt < 2; ++kt) {
            const int ix = (lmod * 128 + 64 + kt * 32 + lhi * 8) ^ ((lmod & 7) << 3);
            lah[kt] = *(const short8*)(a_hi + ix);
            lal[kt] = *(const short8*)(a_lo + ix);
        }
#pragma unroll
        for (int ni = 0; ni < 3; ++ni) {
            if (ni >= ncnt) break;
            f32x4 acc = {lmbias[ni], lmbias[ni], lmbias[ni], lmbias[ni]};
#pragma unroll
            for (int kt = 0; kt < 2; ++kt) {
                acc = __builtin_amdgcn_mfma_f32_16x16x32_bf16(lah[kt], lmh[ni][kt], acc, 0, 0, 0);
                acc = __builtin_amdgcn_mfma_f32_16x16x32_bf16(lah[kt], lml[ni][kt], acc, 0, 0, 0);
                acc = __builtin_amdgcn_mfma_f32_16x16x32_bf16(lal[kt], lmh[ni][kt], acc, 0, 0, 0);
            }
            const int v = (nstart + ni) * 16 + lmod;
            if (v < VOCABSZ) {
#pragma unroll
                for (int e = 0; e < 4; ++e) {
                    const int r = rbase + lhi * 4 + e;
                    out[(size_t)r * (T_STEPS * VOCABSZ) + (size_t)t * VOCABSZ + v] = acc[e];
                }
            }
        }
    }
}

extern "C" void kernel_launch(void* const* d_in, const int* in_sizes, int n_in,
                              void* d_out, int out_size, void* d_ws, size_t ws_size,
                              hipStream_t stream) {
    const int*   idx  = (const int*)  d_in[0];
    const float* wte  = (const float*)d_in[1];
    const float* W_ih = (const float*)d_in[2];
    const float* W_hh = (const float*)d_in[3];
    const float* b_ih = (const float*)d_in[4];
    const float* b_hh = (const float*)d_in[5];
    const float* lm_W = (const float*)d_in[6];
    const float* lm_b = (const float*)d_in[7];
    float* out = (float*)d_out;

    const int B = in_sizes[0] / T_STEPS;   // 4096
    const int grid = B / ROWS;             // 256 blocks -> 1 per CU

    lstm_fused<<<grid, NTHREADS, 0, stream>>>(idx, wte, W_ih, W_hh, b_ih, b_hh,
                                              lm_W, lm_b, out, B);
}